// Round 14
// baseline (5309.135 us; speedup 1.0000x reference)
//
#include <hip/hip_runtime.h>
#include <hip/hip_bf16.h>

typedef __attribute__((ext_vector_type(8))) short shortx8;
typedef __attribute__((ext_vector_type(4))) float f32x4;
typedef __attribute__((ext_vector_type(4))) unsigned short ushortx4;
typedef __attribute__((ext_vector_type(4))) unsigned int u32x4;

#define HDIM 512
#define DDIM 64
#define TSTEPS 512
#define NVG 16     // virtual groups (batch slices of 16); 2 per physical group
#define NB 16
#define SPIN_LIMIT (1u << 18)

// ws byte offsets (identical to round 6)
#define OFF_WHH0 0u
#define OFF_W1   (512u * 1024u)
#define OFF_WIH0 (OFF_W1 + 1024u * 1024u)
#define OFF_B0   (OFF_WIH0 + 64u * 1024u)
#define OFF_B1   (OFF_B0 + 2048u)
#define OFF_H1G  (OFF_B1 + 2048u)             // NVG*2*16KB = 512KB
#define OFF_H2G  (OFF_H1G + 512u * 1024u)     // 512KB
#define OFF_CNT  (OFF_H2G + 512u * 1024u)     // NVG*128B

__device__ __forceinline__ unsigned short f2b(float f) {
    __hip_bfloat16 h = __float2bfloat16(f);
    return *reinterpret_cast<unsigned short*>(&h);
}
__device__ __forceinline__ float b2f(unsigned short s) {
    union { unsigned int u; float f; } cvt;
    cvt.u = ((unsigned int)s) << 16;
    return cvt.f;
}
__device__ __forceinline__ float fast_tanh(float v) {
    float e = __expf(2.f * v);
    return 1.f - 2.f * __builtin_amdgcn_rcpf(e + 1.f);
}

// ---- MALL-homed (Infinity-Cache-coherent) ops: sc0 sc1 = bypass L1+L2 ----
__device__ __forceinline__ void mall_store8(unsigned short* p, ushortx4 v) {
    asm volatile("global_store_dwordx2 %0, %1, off sc0 sc1" :: "v"(p), "v"(v) : "memory");
}
__device__ __forceinline__ shortx8 mall_load16(const unsigned short* p) {
    shortx8 r;
    asm volatile("global_load_dwordx4 %0, %1, off sc0 sc1" : "=v"(r) : "v"(p) : "memory");
    return r;   // NOT waited — consume only after vm_drain, same straight-line block
}
__device__ __forceinline__ void vm_drain() {
    asm volatile("s_waitcnt vmcnt(0)" ::: "memory");
    __builtin_amdgcn_sched_barrier(0);
}
__device__ __forceinline__ void flag_store(unsigned int* p, unsigned int v) {
    asm volatile("global_store_dword %0, %1, off sc0 sc1" :: "v"(p), "v"(v) : "memory");
}
__device__ __forceinline__ bool poll_peers(const unsigned int* fp, int m,
                                           unsigned int tgt, bool bail) {
    if (bail) return false;
    unsigned it = 0;
    for (;;) {
        u32x4 f;
        asm volatile("global_load_dwordx4 %0, %1, off sc0 sc1\n\ts_waitcnt vmcnt(0)"
                     : "=v"(f) : "v"(fp) : "memory");
        bool ok = true;
        if (m != 0 && f[0] < tgt) ok = false;
        if (m != 1 && f[1] < tgt) ok = false;
        if (m != 2 && f[2] < tgt) ok = false;
        if (m != 3 && f[3] < tgt) ok = false;
        if (ok) return true;
        if (++it > SPIN_LIMIT) return false;
    }
}

// ---------------------------------------------------------------------------
// Prep: swizzle weights to MFMA A-fragment-major bf16; fuse biases; zero flags.
// ---------------------------------------------------------------------------
__global__ void prep_kernel(const float* __restrict__ w_ih0, const float* __restrict__ w_hh0,
                            const float* __restrict__ w_ih1, const float* __restrict__ w_hh1,
                            const float* __restrict__ b_ih0, const float* __restrict__ b_hh0,
                            const float* __restrict__ b_ih1, const float* __restrict__ b_hh1,
                            unsigned short* __restrict__ whh0_sw,
                            unsigned short* __restrict__ w1_sw,
                            unsigned short* __restrict__ wih0_sw,
                            float* __restrict__ bias0, float* __restrict__ bias1,
                            unsigned int* __restrict__ cnt)
{
    int idx = blockIdx.x * blockDim.x + threadIdx.x;
    int stride = gridDim.x * blockDim.x;

    for (int i = idx; i < 32 * 16 * 64; i += stride) {
        int l = i & 63, kb = (i >> 6) & 15, mt = i >> 10;
        int row = mt * 16 + (l & 15);
        int k0 = kb * 32 + (l >> 4) * 8;
        unsigned short* o = whh0_sw + (size_t)i * 8;
        #pragma unroll
        for (int j = 0; j < 8; ++j) o[j] = f2b(w_hh0[row * HDIM + k0 + j]);
    }
    for (int i = idx; i < 32 * 32 * 64; i += stride) {
        int l = i & 63, kb = (i >> 6) & 31, mt = i >> 11;
        int row = mt * 16 + (l & 15);
        int k0 = kb * 32 + (l >> 4) * 8;
        unsigned short* o = w1_sw + (size_t)i * 8;
        #pragma unroll
        for (int j = 0; j < 8; ++j) {
            int kk = k0 + j;
            float v = (kk < HDIM) ? w_ih1[row * HDIM + kk] : w_hh1[row * HDIM + (kk - HDIM)];
            o[j] = f2b(v);
        }
    }
    for (int i = idx; i < 32 * 2 * 64; i += stride) {
        int l = i & 63, kb = (i >> 6) & 1, mt = i >> 7;
        int row = mt * 16 + (l & 15);
        int k0 = kb * 32 + (l >> 4) * 8;
        unsigned short* o = wih0_sw + (size_t)i * 8;
        #pragma unroll
        for (int j = 0; j < 8; ++j) o[j] = f2b(w_ih0[row * DDIM + k0 + j]);
    }
    for (int i = idx; i < HDIM; i += stride) {
        bias0[i] = b_ih0[i] + b_hh0[i];
        bias1[i] = b_ih1[i] + b_hh1[i];
    }
    if (idx < NVG * 32) {
        unsigned int z = 0;
        unsigned int* p = cnt + idx;
        asm volatile("global_store_dword %0, %1, off sc0 sc1" :: "v"(p), "v"(z) : "memory");
    }
}

// fused layer0+layer1 compute for one slice (round-6-proven body)
#define FUSED(H1C, XLN, H2N, A0, A1, E0, E1) do {                                   \
    A0 = b0a; A1 = b0b; E0 = b1a; E1 = b1b;                                         \
    _Pragma("unroll")                                                                \
    for (int kb_ = 0; kb_ < 16; ++kb_) {                                             \
        shortx8 bf_ = *(const shortx8*)&(H1C)[kb_ * 512 + lbase];                    \
        A0 = __builtin_amdgcn_mfma_f32_16x16x32_bf16(W0a[kb_], bf_, A0, 0, 0, 0);    \
        A1 = __builtin_amdgcn_mfma_f32_16x16x32_bf16(W0b[kb_], bf_, A1, 0, 0, 0);    \
        E0 = __builtin_amdgcn_mfma_f32_16x16x32_bf16(W1a[kb_], bf_, E0, 0, 0, 0);    \
        E1 = __builtin_amdgcn_mfma_f32_16x16x32_bf16(W1b[kb_], bf_, E1, 0, 0, 0);    \
    }                                                                                \
    _Pragma("unroll")                                                                \
    for (int kx_ = 0; kx_ < 2; ++kx_) {                                              \
        shortx8 bf_ = *(const shortx8*)&(XLN)[kx_ * 512 + lbase];                    \
        A0 = __builtin_amdgcn_mfma_f32_16x16x32_bf16(W0a[16 + kx_], bf_, A0, 0, 0, 0);\
        A1 = __builtin_amdgcn_mfma_f32_16x16x32_bf16(W0b[16 + kx_], bf_, A1, 0, 0, 0);\
    }                                                                                \
    _Pragma("unroll")                                                                \
    for (int kb_ = 0; kb_ < 16; ++kb_) {                                             \
        shortx8 bf_ = *(const shortx8*)&(H2N)[kb_ * 512 + lbase];                    \
        E0 = __builtin_amdgcn_mfma_f32_16x16x32_bf16(W1a[16 + kb_], bf_, E0, 0, 0, 0);\
        E1 = __builtin_amdgcn_mfma_f32_16x16x32_bf16(W1b[16 + kb_], bf_, E1, 0, 0, 0);\
    }                                                                                \
} while (0)

#define PUB4(H1GN, H2GC, A0, A1, E0, E1) do {                                        \
    ushortx4 o0_, o1_, p0_, p1_;                                                     \
    _Pragma("unroll")                                                                \
    for (int j_ = 0; j_ < 4; ++j_) {                                                 \
        o0_[j_] = f2b(fast_tanh((A0)[j_])); o1_[j_] = f2b(fast_tanh((A1)[j_]));      \
        p0_[j_] = f2b(fast_tanh((E0)[j_])); p1_[j_] = f2b(fast_tanh((E1)[j_]));      \
    }                                                                                \
    mall_store8((H1GN) + mt0 * 256 + dbase, o0_);                                    \
    mall_store8((H1GN) + mt1 * 256 + dbase, o1_);                                    \
    mall_store8((H2GC) + mt0 * 256 + dbase, p0_);                                    \
    mall_store8((H2GC) + mt1 * 256 + dbase, p1_);                                    \
} while (0)

// layer-1-only compute (epilogue)
#define L1ONLY(H1C, H2N, E0, E1) do {                                                \
    E0 = b1a; E1 = b1b;                                                              \
    _Pragma("unroll")                                                                \
    for (int kb_ = 0; kb_ < 16; ++kb_) {                                             \
        shortx8 bf_ = *(const shortx8*)&(H1C)[kb_ * 512 + lbase];                    \
        E0 = __builtin_amdgcn_mfma_f32_16x16x32_bf16(W1a[kb_], bf_, E0, 0, 0, 0);    \
        E1 = __builtin_amdgcn_mfma_f32_16x16x32_bf16(W1b[kb_], bf_, E1, 0, 0, 0);    \
    }                                                                                \
    _Pragma("unroll")                                                                \
    for (int kb_ = 0; kb_ < 16; ++kb_) {                                             \
        shortx8 bf_ = *(const shortx8*)&(H2N)[kb_ * 512 + lbase];                    \
        E0 = __builtin_amdgcn_mfma_f32_16x16x32_bf16(W1a[16 + kb_], bf_, E0, 0, 0, 0);\
        E1 = __builtin_amdgcn_mfma_f32_16x16x32_bf16(W1b[16 + kb_], bf_, E1, 0, 0, 0);\
    }                                                                                \
} while (0)

// ---------------------------------------------------------------------------
// 8 physical groups x 4 CUs; each group runs TWO batch slices (vg = 2g, 2g+1)
// with round-6's exact exchange protocol, sync amortized over both slices:
// compute S0 -> publish S0 -> compute S1 (S0 acks in flight) -> publish S1 ->
// drain -> barrier -> flag both -> poll both -> 16 stage loads (straight-line,
// unconditional) -> drain -> LDS writes -> barrier. Hazard structure is
// round 6's per slice (flag v => that member's step v-2 fully complete,
// including stage reads => double-buffer WAR/RAW safe).
// ---------------------------------------------------------------------------
__global__ __launch_bounds__(256, 1) void rnn_pair(
    const float* __restrict__ x,
    const unsigned short* __restrict__ whh0_sw,
    const unsigned short* __restrict__ w1_sw,
    const unsigned short* __restrict__ wih0_sw,
    const float* __restrict__ bias0,
    const float* __restrict__ bias1,
    const float* __restrict__ w_lin,
    const float* __restrict__ b_lin,
    unsigned short* __restrict__ h1G,
    unsigned short* __restrict__ h2G,
    unsigned int* __restrict__ cnt,
    float* __restrict__ out)
{
    __shared__ unsigned short h1L0[2][8192];
    __shared__ unsigned short h2L0[2][8192];
    __shared__ unsigned short h1L1[2][8192];
    __shared__ unsigned short h2L1[2][8192];
    __shared__ unsigned short xL0[2][1024];
    __shared__ unsigned short xL1[2][1024];   // 136KB total -> 1 WG/CU

    const int tid  = threadIdx.x;
    const int w    = tid >> 6;
    const int lane = tid & 63;
    const int gq   = lane >> 4;
    const int col  = lane & 15;
    const int b    = blockIdx.x;
    const int g    = b & 7;                   // physical group; members on one XCD
    const int m    = b >> 3;                  // member 0..3
    const int vg0  = 2 * g, vg1 = 2 * g + 1;  // the two batch slices

    const int mt0 = m * 8 + 2 * w, mt1 = mt0 + 1;
    const int lbase = gq * 128 + col * 8;
    const int dbase = (gq >> 1) * 128 + col * 8 + (gq & 1) * 4;

    unsigned int* flags0 = cnt + vg0 * 32;
    unsigned int* flags1 = cnt + vg1 * 32;

    // ---- weights -> registers, once; pinned ----
    shortx8 W0a[18], W0b[18], W1a[32], W1b[32];
    #pragma unroll
    for (int kb = 0; kb < 16; ++kb) {
        W0a[kb] = *(const shortx8*)(whh0_sw + (((size_t)(mt0 * 16 + kb)) << 9) + lane * 8);
        W0b[kb] = *(const shortx8*)(whh0_sw + (((size_t)(mt1 * 16 + kb)) << 9) + lane * 8);
    }
    #pragma unroll
    for (int kx = 0; kx < 2; ++kx) {
        W0a[16 + kx] = *(const shortx8*)(wih0_sw + (((size_t)(mt0 * 2 + kx)) << 9) + lane * 8);
        W0b[16 + kx] = *(const shortx8*)(wih0_sw + (((size_t)(mt1 * 2 + kx)) << 9) + lane * 8);
    }
    #pragma unroll
    for (int kb = 0; kb < 32; ++kb) {
        W1a[kb] = *(const shortx8*)(w1_sw + (((size_t)(mt0 * 32 + kb)) << 9) + lane * 8);
        W1b[kb] = *(const shortx8*)(w1_sw + (((size_t)(mt1 * 32 + kb)) << 9) + lane * 8);
    }
    #pragma unroll
    for (int i = 0; i < 18; ++i) { asm volatile("" : "+v"(W0a[i]), "+v"(W0b[i])); }
    #pragma unroll
    for (int i = 0; i < 32; ++i) { asm volatile("" : "+v"(W1a[i]), "+v"(W1b[i])); }

    f32x4 b0a = *(const f32x4*)(bias0 + mt0 * 16 + gq * 4);
    f32x4 b0b = *(const f32x4*)(bias0 + mt1 * 16 + gq * 4);
    f32x4 b1a = *(const f32x4*)(bias1 + mt0 * 16 + gq * 4);
    f32x4 b1b = *(const f32x4*)(bias1 + mt1 * 16 + gq * 4);

    const int bb = tid >> 4, d4 = (tid & 15) * 4;
    const int xo = ((d4 >> 3) * 16 + bb) * 8 + (d4 & 7);
    const float* xrow0 = x + (size_t)(vg0 * NB + bb) * TSTEPS * DDIM + d4;
    const float* xrow1 = x + (size_t)(vg1 * NB + bb) * TSTEPS * DDIM + d4;
    bool bail = false;

    // ---- prologue: x(0),x(1) staged; h2(-1)=0; h1(0) exchanged (both slices)
    {
        f32x4 x00 = *(const f32x4*)(xrow0);
        f32x4 x01 = *(const f32x4*)(xrow0 + DDIM);
        f32x4 x10 = *(const f32x4*)(xrow1);
        f32x4 x11 = *(const f32x4*)(xrow1 + DDIM);
        ushortx4 a, c;
        #pragma unroll
        for (int j = 0; j < 4; ++j) { a[j] = f2b(x00[j]); c[j] = f2b(x01[j]); }
        *(ushortx4*)&xL0[0][xo] = a;
        *(ushortx4*)&xL0[1][xo] = c;
        #pragma unroll
        for (int j = 0; j < 4; ++j) { a[j] = f2b(x10[j]); c[j] = f2b(x11[j]); }
        *(ushortx4*)&xL1[0][xo] = a;
        *(ushortx4*)&xL1[1][xo] = c;
        shortx8 zz = {0, 0, 0, 0, 0, 0, 0, 0};
        for (int i = tid * 8; i < 8192; i += 2048) {
            *(shortx8*)&h2L0[1][i] = zz;
            *(shortx8*)&h2L1[1][i] = zz;
        }
    }
    __syncthreads();
    {
        unsigned short* h1G00 = h1G + (size_t)(vg0 * 2 + 0) * 8192;
        unsigned short* h1G01 = h1G + (size_t)(vg1 * 2 + 0) * 8192;
        // h1(0) = tanh(wih0 @ x(0) + b0), slice 0 then slice 1
        f32x4 acc0 = b0a, acc1 = b0b;
        #pragma unroll
        for (int kx = 0; kx < 2; ++kx) {
            shortx8 bf = *(const shortx8*)&xL0[0][kx * 512 + lbase];
            acc0 = __builtin_amdgcn_mfma_f32_16x16x32_bf16(W0a[16 + kx], bf, acc0, 0, 0, 0);
            acc1 = __builtin_amdgcn_mfma_f32_16x16x32_bf16(W0b[16 + kx], bf, acc1, 0, 0, 0);
        }
        {
            ushortx4 o0, o1;
            #pragma unroll
            for (int j = 0; j < 4; ++j) { o0[j] = f2b(fast_tanh(acc0[j])); o1[j] = f2b(fast_tanh(acc1[j])); }
            mall_store8(h1G00 + mt0 * 256 + dbase, o0);
            mall_store8(h1G00 + mt1 * 256 + dbase, o1);
        }
        acc0 = b0a; acc1 = b0b;
        #pragma unroll
        for (int kx = 0; kx < 2; ++kx) {
            shortx8 bf = *(const shortx8*)&xL1[0][kx * 512 + lbase];
            acc0 = __builtin_amdgcn_mfma_f32_16x16x32_bf16(W0a[16 + kx], bf, acc0, 0, 0, 0);
            acc1 = __builtin_amdgcn_mfma_f32_16x16x32_bf16(W0b[16 + kx], bf, acc1, 0, 0, 0);
        }
        {
            ushortx4 o0, o1;
            #pragma unroll
            for (int j = 0; j < 4; ++j) { o0[j] = f2b(fast_tanh(acc0[j])); o1[j] = f2b(fast_tanh(acc1[j])); }
            mall_store8(h1G01 + mt0 * 256 + dbase, o0);
            mall_store8(h1G01 + mt1 * 256 + dbase, o1);
        }
        vm_drain();
        __syncthreads();
        if (tid == 0) { flag_store(flags0 + m, 1u); flag_store(flags1 + m, 1u); }
        if (!poll_peers(flags0, m, 1u, bail)) bail = true;
        if (!poll_peers(flags1, m, 1u, bail)) bail = true;
        const int o = tid * 8;
        shortx8 v0 = mall_load16(h1G00 + o);
        shortx8 v1 = mall_load16(h1G00 + o + 2048);
        shortx8 v2 = mall_load16(h1G00 + o + 4096);
        shortx8 v3 = mall_load16(h1G00 + o + 6144);
        shortx8 u0 = mall_load16(h1G01 + o);
        shortx8 u1 = mall_load16(h1G01 + o + 2048);
        shortx8 u2 = mall_load16(h1G01 + o + 4096);
        shortx8 u3 = mall_load16(h1G01 + o + 6144);
        vm_drain();
        *(shortx8*)&h1L0[0][o]        = v0;
        *(shortx8*)&h1L0[0][o + 2048] = v1;
        *(shortx8*)&h1L0[0][o + 4096] = v2;
        *(shortx8*)&h1L0[0][o + 6144] = v3;
        *(shortx8*)&h1L1[0][o]        = u0;
        *(shortx8*)&h1L1[0][o + 2048] = u1;
        *(shortx8*)&h1L1[0][o + 4096] = u2;
        *(shortx8*)&h1L1[0][o + 6144] = u3;
    }
    __syncthreads();

    // ---- main loop: iteration t advances BOTH slices one step ----
    for (int t = 0; t < TSTEPS - 1; ++t) {
        const int pc = t & 1, pn = pc ^ 1;
        unsigned short* h1Gn0 = h1G + (size_t)(vg0 * 2 + pn) * 8192;
        unsigned short* h2Gc0 = h2G + (size_t)(vg0 * 2 + pc) * 8192;
        unsigned short* h1Gn1 = h1G + (size_t)(vg1 * 2 + pn) * 8192;
        unsigned short* h2Gc1 = h2G + (size_t)(vg1 * 2 + pc) * 8192;

        const bool havex = (t + 2 < TSTEPS);
        f32x4 xv0, xv1;
        if (havex) {
            xv0 = *(const f32x4*)(xrow0 + (size_t)(t + 2) * DDIM);
            xv1 = *(const f32x4*)(xrow1 + (size_t)(t + 2) * DDIM);
        }

        // S0: fused compute + publish
        {
            f32x4 A0, A1, E0, E1;
            FUSED(h1L0[pc], xL0[pn], h2L0[pn], A0, A1, E0, E1);
            PUB4(h1Gn0, h2Gc0, A0, A1, E0, E1);
        }
        // S1: fused compute + publish (S0 store-acks fly underneath)
        {
            f32x4 A0, A1, E0, E1;
            FUSED(h1L1[pc], xL1[pn], h2L1[pn], A0, A1, E0, E1);
            PUB4(h1Gn1, h2Gc1, A0, A1, E0, E1);
        }
        vm_drain();
        __syncthreads();

        const unsigned int tgt = (unsigned int)(t + 2);
        if (tid == 0) { flag_store(flags0 + m, tgt); flag_store(flags1 + m, tgt); }
        if (!poll_peers(flags0, m, tgt, bail)) bail = true;
        if (!poll_peers(flags1, m, tgt, bail)) bail = true;

        // stage both slices: 16 unconditional straight-line loads, one drain
        const int o = tid * 8;
        shortx8 va0 = mall_load16(h1Gn0 + o);
        shortx8 va1 = mall_load16(h1Gn0 + o + 2048);
        shortx8 va2 = mall_load16(h1Gn0 + o + 4096);
        shortx8 va3 = mall_load16(h1Gn0 + o + 6144);
        shortx8 vb0 = mall_load16(h2Gc0 + o);
        shortx8 vb1 = mall_load16(h2Gc0 + o + 2048);
        shortx8 vb2 = mall_load16(h2Gc0 + o + 4096);
        shortx8 vb3 = mall_load16(h2Gc0 + o + 6144);
        shortx8 vc0 = mall_load16(h1Gn1 + o);
        shortx8 vc1 = mall_load16(h1Gn1 + o + 2048);
        shortx8 vc2 = mall_load16(h1Gn1 + o + 4096);
        shortx8 vc3 = mall_load16(h1Gn1 + o + 6144);
        shortx8 vd0 = mall_load16(h2Gc1 + o);
        shortx8 vd1 = mall_load16(h2Gc1 + o + 2048);
        shortx8 vd2 = mall_load16(h2Gc1 + o + 4096);
        shortx8 vd3 = mall_load16(h2Gc1 + o + 6144);
        vm_drain();
        *(shortx8*)&h1L0[pn][o]        = va0;
        *(shortx8*)&h1L0[pn][o + 2048] = va1;
        *(shortx8*)&h1L0[pn][o + 4096] = va2;
        *(shortx8*)&h1L0[pn][o + 6144] = va3;
        *(shortx8*)&h2L0[pc][o]        = vb0;
        *(shortx8*)&h2L0[pc][o + 2048] = vb1;
        *(shortx8*)&h2L0[pc][o + 4096] = vb2;
        *(shortx8*)&h2L0[pc][o + 6144] = vb3;
        *(shortx8*)&h1L1[pn][o]        = vc0;
        *(shortx8*)&h1L1[pn][o + 2048] = vc1;
        *(shortx8*)&h1L1[pn][o + 4096] = vc2;
        *(shortx8*)&h1L1[pn][o + 6144] = vc3;
        *(shortx8*)&h2L1[pc][o]        = vd0;
        *(shortx8*)&h2L1[pc][o + 2048] = vd1;
        *(shortx8*)&h2L1[pc][o + 4096] = vd2;
        *(shortx8*)&h2L1[pc][o + 6144] = vd3;
        if (havex) {
            ushortx4 ox;
            #pragma unroll
            for (int j = 0; j < 4; ++j) ox[j] = f2b(xv0[j]);
            *(ushortx4*)&xL0[pc][xo] = ox;
            #pragma unroll
            for (int j = 0; j < 4; ++j) ox[j] = f2b(xv1[j]);
            *(ushortx4*)&xL1[pc][xo] = ox;
        }
        __syncthreads();
    }

    // ---- epilogue: h2(511) per slice; final linear on member 0 ----
    {
        unsigned short* h2G10 = h2G + (size_t)(vg0 * 2 + 1) * 8192;
        unsigned short* h2G11 = h2G + (size_t)(vg1 * 2 + 1) * 8192;
        {
            f32x4 E0, E1;
            L1ONLY(h1L0[1], h2L0[0], E0, E1);
            ushortx4 p0, p1;
            #pragma unroll
            for (int j = 0; j < 4; ++j) { p0[j] = f2b(fast_tanh(E0[j])); p1[j] = f2b(fast_tanh(E1[j])); }
            mall_store8(h2G10 + mt0 * 256 + dbase, p0);
            mall_store8(h2G10 + mt1 * 256 + dbase, p1);
        }
        {
            f32x4 E0, E1;
            L1ONLY(h1L1[1], h2L1[0], E0, E1);
            ushortx4 p0, p1;
            #pragma unroll
            for (int j = 0; j < 4; ++j) { p0[j] = f2b(fast_tanh(E0[j])); p1[j] = f2b(fast_tanh(E1[j])); }
            mall_store8(h2G11 + mt0 * 256 + dbase, p0);
            mall_store8(h2G11 + mt1 * 256 + dbase, p1);
        }
        vm_drain();
        __syncthreads();
        if (tid == 0) {
            flag_store(flags0 + m, (unsigned int)(TSTEPS + 1));
            flag_store(flags1 + m, (unsigned int)(TSTEPS + 1));
        }
        if (m == 0) {
            if (!poll_peers(flags0, m, (unsigned int)(TSTEPS + 1), bail)) bail = true;
            if (!poll_peers(flags1, m, (unsigned int)(TSTEPS + 1), bail)) bail = true;
            #pragma unroll
            for (int r = 0; r < 4; ++r) {
                int bx = w * 4 + r;
                shortx8 hv = mall_load16(h2G10 + lane * 128 + bx * 8);
                vm_drain();
                float s = 0.f;
                #pragma unroll
                for (int j = 0; j < 8; ++j)
                    s += b2f((unsigned short)hv[j]) * w_lin[lane * 8 + j];
                #pragma unroll
                for (int off = 32; off; off >>= 1) s += __shfl_xor(s, off);
                if (lane == 0) out[vg0 * NB + bx] = s + b_lin[0];
            }
            #pragma unroll
            for (int r = 0; r < 4; ++r) {
                int bx = w * 4 + r;
                shortx8 hv = mall_load16(h2G11 + lane * 128 + bx * 8);
                vm_drain();
                float s = 0.f;
                #pragma unroll
                for (int j = 0; j < 8; ++j)
                    s += b2f((unsigned short)hv[j]) * w_lin[lane * 8 + j];
                #pragma unroll
                for (int off = 32; off; off >>= 1) s += __shfl_xor(s, off);
                if (lane == 0) out[vg1 * NB + bx] = s + b_lin[0];
            }
        }
    }
    if (bail && tid == 0 && b == 0) out[0] = out[0];  // keep bail live
}

extern "C" void kernel_launch(void* const* d_in, const int* in_sizes, int n_in,
                              void* d_out, int out_size, void* d_ws, size_t ws_size,
                              hipStream_t stream) {
    const float* x     = (const float*)d_in[0];
    const float* w_ih0 = (const float*)d_in[1];
    const float* w_hh0 = (const float*)d_in[2];
    const float* b_ih0 = (const float*)d_in[3];
    const float* b_hh0 = (const float*)d_in[4];
    const float* w_ih1 = (const float*)d_in[5];
    const float* w_hh1 = (const float*)d_in[6];
    const float* b_ih1 = (const float*)d_in[7];
    const float* b_hh1 = (const float*)d_in[8];
    const float* w_lin = (const float*)d_in[9];
    const float* b_lin = (const float*)d_in[10];
    float* out = (float*)d_out;

    char* ws = (char*)d_ws;
    unsigned short* whh0_sw = (unsigned short*)(ws + OFF_WHH0);
    unsigned short* w1_sw   = (unsigned short*)(ws + OFF_W1);
    unsigned short* wih0_sw = (unsigned short*)(ws + OFF_WIH0);
    float* bias0            = (float*)(ws + OFF_B0);
    float* bias1            = (float*)(ws + OFF_B1);
    unsigned short* h1G     = (unsigned short*)(ws + OFF_H1G);
    unsigned short* h2G     = (unsigned short*)(ws + OFF_H2G);
    unsigned int*   cnt     = (unsigned int*)(ws + OFF_CNT);

    prep_kernel<<<416, 256, 0, stream>>>(w_ih0, w_hh0, w_ih1, w_hh1,
                                         b_ih0, b_hh0, b_ih1, b_hh1,
                                         whh0_sw, w1_sw, wih0_sw, bias0, bias1, cnt);
    rnn_pair<<<32, 256, 0, stream>>>(x, whh0_sw, w1_sw, wih0_sw, bias0, bias1,
                                     w_lin, b_lin, h1G, h2G, cnt, out);
}